// Round 5
// baseline (609.002 us; speedup 1.0000x reference)
//
#include <hip/hip_runtime.h>
#include <hip/hip_bf16.h>

// FourierKANLayer: N=4096, D_IN=512, D_OUT=512, G=32
// y = [cos/sin(k*LN(x)) features] @ W + bias  == GEMM M=4096,N=512,K=32768 (bf16 MFMA)
// R5: barrier-free GEMM. A generated per-lane in registers (K-permuted harmonics,
//     stride-4 Chebyshev). B direct global 16B frags (K-permuted weights). No LDS.
// ws layout: [0,16MB)  csT float2[512][4096] = (cos xn, sin xn) transposed seeds
//            [16MB]    mu_rs float2[4096] (32 KB)
//            [17MB]    bf16 weights [2][512][16384], K-PERMUTED (33.5 MB)
//            [51MB]    bf16 split-K partials [8][4096][512] (33.5 MB)

#define N_ROWS 4096
#define D_IN   512
#define D_OUT  512
#define KT     16384   // per-trig K = D_IN*G
#define BM 128
#define BN 128

typedef short short8 __attribute__((ext_vector_type(8)));
typedef float float4v __attribute__((ext_vector_type(4)));

__device__ inline unsigned int pack2bf(float a, float b) {
    __hip_bfloat162 h = __float22bfloat162_rn(make_float2(a, b));
    union { __hip_bfloat162 h; unsigned int u; } cv;
    cv.h = h;
    return cv.u;
}

__device__ inline unsigned short bf16_1(float a) {
    union { float f; unsigned int u; } cv;
    cv.f = a;
    unsigned int r = (cv.u + 0x7fff + ((cv.u >> 16) & 1)) >> 16;  // RN-even
    return (unsigned short)r;
}

// ---- kernel 1: per-row LayerNorm stats (mu, rsqrt(var+eps)) ----
__global__ __launch_bounds__(256) void ln_stats(const float* __restrict__ x,
        float2* __restrict__ mu_rs) {
    const int t = threadIdx.x;
    const int row = blockIdx.x * 4 + (t >> 6);
    const int lane = t & 63;
    const float4* xr = (const float4*)(x + (size_t)row * D_IN);
    float4 a = xr[lane];
    float4 c = xr[lane + 64];
    float s = a.x + a.y + a.z + a.w + c.x + c.y + c.z + c.w;
    float q = a.x * a.x + a.y * a.y + a.z * a.z + a.w * a.w
            + c.x * c.x + c.y * c.y + c.z * c.z + c.w * c.w;
    #pragma unroll
    for (int off = 32; off > 0; off >>= 1) {
        s += __shfl_down(s, off, 64);
        q += __shfl_down(q, off, 64);
    }
    if (lane == 0) {
        float mu = s * (1.f / D_IN);
        float var = q * (1.f / D_IN) - mu * mu;
        mu_rs[row] = make_float2(mu, rsqrtf(var + 1e-5f));
    }
}

// ---- kernel 2: normalize + sincos seeds, transposed coalesced write ----
__global__ __launch_bounds__(256) void feat_seed(const float* __restrict__ x,
        const float* __restrict__ w, const float* __restrict__ b,
        const float2* __restrict__ mu_rs, float2* __restrict__ csT) {
    __shared__ float2 tile[64][66];
    const int t = threadIdx.x;
    const int r0 = blockIdx.x * 64, i0 = blockIdx.y * 64;
    const int rr = t >> 6;      // 0..3
    const int cc = t & 63;
    const float wv = w[i0 + cc], bv = b[i0 + cc];
    #pragma unroll
    for (int p = 0; p < 16; ++p) {
        const int row = r0 + p * 4 + rr;
        float v = x[(size_t)row * D_IN + i0 + cc];
        float2 mr = mu_rs[row];
        float xn = (v - mr.x) * mr.y * wv + bv;
        float sn, cn;
        __sincosf(xn, &sn, &cn);
        tile[cc][p * 4 + rr] = make_float2(cn, sn);
    }
    __syncthreads();
    #pragma unroll
    for (int p = 0; p < 16; ++p) {
        const int dim = p * 4 + rr;
        csT[(size_t)(i0 + dim) * N_ROWS + r0 + cc] = tile[dim][cc];
    }
}

// ---- kernel 3: cast+PERMUTE fouriercoeffs fp32 -> bf16 ----
// Wb[t][o][i][k'] holds W[t][o][i][g] at k' = (g&3)*8 + (g>>2), i.e. the
// harmonic assigned to MFMA k-position lq*8+j is g = j*4 + lq (stride-4 runs).
__global__ __launch_bounds__(256) void cvt_kernel(const float* __restrict__ fc,
        unsigned short* __restrict__ Wb) {
    const size_t r = (size_t)blockIdx.x * 256 + threadIdx.x;  // (t,o,i) row id
    const float* src = fc + r * 32;
    float v[32];
    #pragma unroll
    for (int c = 0; c < 8; ++c) {
        float4 f = ((const float4*)src)[c];
        v[c * 4 + 0] = f.x; v[c * 4 + 1] = f.y;
        v[c * 4 + 2] = f.z; v[c * 4 + 3] = f.w;
    }
    unsigned int o[16];
    #pragma unroll
    for (int p = 0; p < 16; ++p) {
        const int ka = p * 2, kb = p * 2 + 1;
        const int ga = (ka & 7) * 4 + (ka >> 3);
        const int gb = (kb & 7) * 4 + (kb >> 3);
        o[p] = pack2bf(v[ga], v[gb]);
    }
    uint4* dst = (uint4*)(Wb + r * 32);
    dst[0] = make_uint4(o[0], o[1], o[2], o[3]);
    dst[1] = make_uint4(o[4], o[5], o[6], o[7]);
    dst[2] = make_uint4(o[8], o[9], o[10], o[11]);
    dst[3] = make_uint4(o[12], o[13], o[14], o[15]);
}

// ---- per-lane A-fragment generation ----
// Lane (lm,lq): element j of the returned short8 = trig((j*4+lq+1) * theta),
// via step-4 Chebyshev: V(n+4) = 2cos(4th)*V(n) - V(n-4). No branches on lq.
__device__ inline short8 gen_af(float2 cs, int ttype, bool b0, bool b1) {
    const float c1 = cs.x, s1v = cs.y;
    const float c2v = c1 + c1;
    const float C2 = __builtin_fmaf(c2v, c1, -1.f);
    float cur, add1, c42;
    if (ttype == 0) {  // cos chain; cur=C(lq+1), first addend = -C(3-lq)
        const float C3 = __builtin_fmaf(c2v, C2, -c1);
        const float C4 = __builtin_fmaf(c2v, C3, -C2);
        c42 = C4 + C4;
        cur  = b1 ? (b0 ? C4 : C3) : (b0 ? C2 : c1);
        add1 = b1 ? (b0 ? -1.f : -c1) : (b0 ? -C2 : -C3);
    } else {           // sin chain; cur=S(lq+1), first addend = +S(3-lq)
        const float S2 = c2v * s1v;
        const float S3 = __builtin_fmaf(c2v, S2, -s1v);
        const float S4 = __builtin_fmaf(c2v, S3, -S2);
        const float C22 = C2 + C2;
        const float C4 = __builtin_fmaf(C22, C2, -1.f);
        c42 = C4 + C4;
        cur  = b1 ? (b0 ? S4 : S3) : (b0 ? S2 : s1v);
        add1 = b1 ? (b0 ? 0.f : s1v) : (b0 ? S2 : S3);
    }
    const float v0 = cur;
    const float v1 = __builtin_fmaf(c42, v0, add1);
    const float v2 = __builtin_fmaf(c42, v1, -v0);
    const float v3 = __builtin_fmaf(c42, v2, -v1);
    const float v4 = __builtin_fmaf(c42, v3, -v2);
    const float v5 = __builtin_fmaf(c42, v4, -v3);
    const float v6 = __builtin_fmaf(c42, v5, -v4);
    const float v7 = __builtin_fmaf(c42, v6, -v5);
    union { short8 s; unsigned int u[4]; } r;
    r.u[0] = pack2bf(v0, v1);
    r.u[1] = pack2bf(v2, v3);
    r.u[2] = pack2bf(v4, v5);
    r.u[3] = pack2bf(v6, v7);
    return r.s;
}

// ---- kernel 4: barrier-free fused GEMM, split-K=8 ----
// 4 waves/block, wave tile 32x128 (M-private). A in regs, B in regs, no LDS.
__global__ __launch_bounds__(256, 3) void fkan_gemm(const float2* __restrict__ csT,
        const unsigned short* __restrict__ Wb, unsigned short* __restrict__ pb) {
    const int t = threadIdx.x;
    const int row0 = blockIdx.x * BM;
    const int col0 = blockIdx.y * BN;
    const int chunk = blockIdx.z;
    const int ttype = chunk >> 2;
    const int k0 = (chunk & 3) * 4096;   // within-trig k offset
    const int i0 = k0 >> 5;              // starting input dim for this chunk
    const int l = t & 63, wv = t >> 6;
    const int lm = l & 15, lq = l >> 4;
    const int wrow = wv * 32;            // wave-private row window
    const bool b0 = lq & 1, b1 = lq & 2;

    // B: col = col0 + tn*16 + lm (K-major, permuted); lane k-offset lq*8
    const unsigned short* Wt = Wb + (size_t)ttype * D_OUT * KT
                             + (size_t)(col0 + lm) * KT + k0 + lq * 8;
    // seeds: csT[dim][row], row = row0 + wrow + tm*16 + lm
    const float2* csBase = csT + (size_t)i0 * N_ROWS + row0 + wrow + lm;

    float4v acc[2][8];
    #pragma unroll
    for (int i = 0; i < 2; ++i)
        #pragma unroll
        for (int j = 0; j < 8; ++j)
            acc[i][j] = (float4v){0.f, 0.f, 0.f, 0.f};

    short8 bfr0[8], bfr1[8];
    #pragma unroll
    for (int tn = 0; tn < 8; ++tn)   // B(iter0, h=0)
        bfr0[tn] = *(const short8*)(Wt + (size_t)tn * 16 * KT);

    float2 cs[4];                    // combo c = tm*2 + h, iter 0
    #pragma unroll
    for (int c = 0; c < 4; ++c)
        cs[c] = csBase[(size_t)(c & 1) * N_ROWS + (c >> 1) * 16];

    for (int iter = 0; iter < 64; ++iter) {
        const unsigned short* wk = Wt + iter * 64;
        #pragma unroll
        for (int tn = 0; tn < 8; ++tn)   // B(iter, h=1)
            bfr1[tn] = *(const short8*)(wk + (size_t)tn * 16 * KT + 32);
        float2 csN[4];
        if (iter < 63) {
            #pragma unroll
            for (int c = 0; c < 4; ++c)
                csN[c] = csBase[(size_t)((iter + 1) * 2 + (c & 1)) * N_ROWS
                                + (c >> 1) * 16];
        }
        // ---- h = 0 (uses bfr0)
        #pragma unroll
        for (int tm = 0; tm < 2; ++tm) {
            const short8 af = gen_af(cs[tm * 2], ttype, b0, b1);
            #pragma unroll
            for (int tn = 0; tn < 8; ++tn)
                acc[tm][tn] = __builtin_amdgcn_mfma_f32_16x16x32_bf16(
                    af, bfr0[tn], acc[tm][tn], 0, 0, 0);
        }
        if (iter < 63) {
            #pragma unroll
            for (int tn = 0; tn < 8; ++tn)   // B(iter+1, h=0)
                bfr0[tn] = *(const short8*)(wk + 64 + (size_t)tn * 16 * KT);
        }
        // ---- h = 1 (uses bfr1)
        #pragma unroll
        for (int tm = 0; tm < 2; ++tm) {
            const short8 af = gen_af(cs[tm * 2 + 1], ttype, b0, b1);
            #pragma unroll
            for (int tn = 0; tn < 8; ++tn)
                acc[tm][tn] = __builtin_amdgcn_mfma_f32_16x16x32_bf16(
                    af, bfr1[tn], acc[tm][tn], 0, 0, 0);
        }
        #pragma unroll
        for (int c = 0; c < 4; ++c)
            cs[c] = csN[c];
    }
    // epilogue: C/D layout col=lane&15, row=quad*4+reg (m89-verified)
    unsigned short* pc = pb + (size_t)chunk * N_ROWS * D_OUT;
    #pragma unroll
    for (int tm = 0; tm < 2; ++tm)
        #pragma unroll
        for (int tn = 0; tn < 8; ++tn)
            #pragma unroll
            for (int r = 0; r < 4; ++r) {
                const int row = row0 + wrow + tm * 16 + lq * 4 + r;
                const int col = col0 + tn * 16 + lm;
                pc[(size_t)row * D_OUT + col] = bf16_1(acc[tm][tn][r]);
            }
}

// ---- kernel 5: out = bias + sum of 8 bf16 partials (coalesced) ----
__global__ __launch_bounds__(256) void reduce_kernel(const unsigned short* __restrict__ pb,
        const float* __restrict__ bias, float* __restrict__ out) {
    const size_t e = ((size_t)blockIdx.x * 256 + threadIdx.x) * 4;
    const int col = (int)(e & (D_OUT - 1));
    float4 s = *(const float4*)(bias + col);
    #pragma unroll
    for (int c = 0; c < 8; ++c) {
        ushort4 u = *(const ushort4*)(pb + (size_t)c * N_ROWS * D_OUT + e);
        union { unsigned int u; float f; } f0, f1, f2, f3;
        f0.u = (unsigned int)u.x << 16;
        f1.u = (unsigned int)u.y << 16;
        f2.u = (unsigned int)u.z << 16;
        f3.u = (unsigned int)u.w << 16;
        s.x += f0.f; s.y += f1.f; s.z += f2.f; s.w += f3.f;
    }
    *(float4*)(out + e) = s;
}

extern "C" void kernel_launch(void* const* d_in, const int* in_sizes, int n_in,
                              void* d_out, int out_size, void* d_ws, size_t ws_size,
                              hipStream_t stream) {
    const float* x    = (const float*)d_in[0];
    const float* ln_w = (const float*)d_in[1];
    const float* ln_b = (const float*)d_in[2];
    const float* fc   = (const float*)d_in[3];
    const float* bias = (const float*)d_in[4];
    float* out = (float*)d_out;

    float2* csT = (float2*)d_ws;                                        // 16 MB
    float2* mu_rs = (float2*)((char*)d_ws + (16u << 20));               // 32 KB
    unsigned short* Wb = (unsigned short*)((char*)d_ws + (17u << 20));  // 33.5 MB
    unsigned short* pbp = (unsigned short*)((char*)d_ws + (51u << 20)); // 33.5 MB

    ln_stats<<<N_ROWS / 4, 256, 0, stream>>>(x, mu_rs);
    feat_seed<<<dim3(N_ROWS / 64, D_IN / 64), 256, 0, stream>>>(x, ln_w, ln_b, mu_rs, csT);
    cvt_kernel<<<2048, 256, 0, stream>>>(fc, Wb);                       // 524288 rows
    fkan_gemm<<<dim3(N_ROWS / BM, D_OUT / BN, 8), 256, 0, stream>>>(csT, Wb, pbp);
    reduce_kernel<<<2048, 256, 0, stream>>>(pbp, bias, out);            // 2.10M outs
}

// Round 6
// 543.896 us; speedup vs baseline: 1.1197x; 1.1197x over previous
//
#include <hip/hip_runtime.h>
#include <hip/hip_bf16.h>

// FourierKANLayer: N=4096, D_IN=512, D_OUT=512, G=32
// y = [cos/sin(k*LN(x)) features] @ W + bias  == GEMM M=4096,N=512,K=32768 (bf16 MFMA)
// R6 = R4 skeleton (A dbuf LDS, 1 barrier/iter, B direct global) + full-iteration
//      B register ping-pong (compile-time parity, no dynamic reg indexing).
// ws layout: [0,16MB)  csT float2[512][4096] = (cos xn, sin xn) transposed seeds
//            [16MB]    mu_rs float2[4096] (32 KB)
//            [17MB]    bf16 weights [2][512][16384] K-major (33.5 MB)
//            [51MB]    bf16 split-K partials [8][4096][512] (33.5 MB)

#define N_ROWS 4096
#define D_IN   512
#define D_OUT  512
#define KT     16384   // per-trig K = D_IN*G
#define BM 128
#define BN 128
#define LDA 72         // padded LDS leading dim (bf16 units); 144B rows keep 16B align

typedef short short8 __attribute__((ext_vector_type(8)));
typedef float float4v __attribute__((ext_vector_type(4)));

__device__ inline unsigned int pack2bf(float a, float b) {
    __hip_bfloat162 h = __float22bfloat162_rn(make_float2(a, b));
    union { __hip_bfloat162 h; unsigned int u; } cv;
    cv.h = h;
    return cv.u;
}

__device__ inline unsigned short bf16_1(float a) {
    union { float f; unsigned int u; } cv;
    cv.f = a;
    unsigned int r = (cv.u + 0x7fff + ((cv.u >> 16) & 1)) >> 16;  // RN-even
    return (unsigned short)r;
}

// ---- kernel 1: per-row LayerNorm stats (mu, rsqrt(var+eps)) ----
__global__ __launch_bounds__(256) void ln_stats(const float* __restrict__ x,
        float2* __restrict__ mu_rs) {
    const int t = threadIdx.x;
    const int row = blockIdx.x * 4 + (t >> 6);
    const int lane = t & 63;
    const float4* xr = (const float4*)(x + (size_t)row * D_IN);
    float4 a = xr[lane];
    float4 c = xr[lane + 64];
    float s = a.x + a.y + a.z + a.w + c.x + c.y + c.z + c.w;
    float q = a.x * a.x + a.y * a.y + a.z * a.z + a.w * a.w
            + c.x * c.x + c.y * c.y + c.z * c.z + c.w * c.w;
    #pragma unroll
    for (int off = 32; off > 0; off >>= 1) {
        s += __shfl_down(s, off, 64);
        q += __shfl_down(q, off, 64);
    }
    if (lane == 0) {
        float mu = s * (1.f / D_IN);
        float var = q * (1.f / D_IN) - mu * mu;
        mu_rs[row] = make_float2(mu, rsqrtf(var + 1e-5f));
    }
}

// ---- kernel 2: normalize + sincos seeds, transposed coalesced write ----
__global__ __launch_bounds__(256) void feat_seed(const float* __restrict__ x,
        const float* __restrict__ w, const float* __restrict__ b,
        const float2* __restrict__ mu_rs, float2* __restrict__ csT) {
    __shared__ float2 tile[64][66];
    const int t = threadIdx.x;
    const int r0 = blockIdx.x * 64, i0 = blockIdx.y * 64;
    const int rr = t >> 6;      // 0..3
    const int cc = t & 63;
    const float wv = w[i0 + cc], bv = b[i0 + cc];
    #pragma unroll
    for (int p = 0; p < 16; ++p) {
        const int row = r0 + p * 4 + rr;
        float v = x[(size_t)row * D_IN + i0 + cc];
        float2 mr = mu_rs[row];
        float xn = (v - mr.x) * mr.y * wv + bv;
        float sn, cn;
        __sincosf(xn, &sn, &cn);
        tile[cc][p * 4 + rr] = make_float2(cn, sn);
    }
    __syncthreads();
    #pragma unroll
    for (int p = 0; p < 16; ++p) {
        const int dim = p * 4 + rr;
        csT[(size_t)(i0 + dim) * N_ROWS + r0 + cc] = tile[dim][cc];
    }
}

// ---- kernel 3: cast fouriercoeffs fp32 -> bf16 (layout preserved: [t][o][i*32+g]) ----
__global__ __launch_bounds__(256) void cvt_kernel(const float* __restrict__ fc,
        unsigned short* __restrict__ Wb) {
    size_t e = ((size_t)blockIdx.x * 256 + threadIdx.x) * 8;
    const float4* in = (const float4*)(fc + e);
    float4 a = in[0];
    float4 c = in[1];
    uint4 o;
    o.x = pack2bf(a.x, a.y);
    o.y = pack2bf(a.z, a.w);
    o.z = pack2bf(c.x, c.y);
    o.w = pack2bf(c.z, c.w);
    *(uint4*)(Wb + e) = o;
}

// ---- helpers for the GEMM K-loop ----
__device__ inline void stage_feats(unsigned short* AsDst, float2 cs, int ttype,
                                   int frow, int ihalf) {
    const float c1 = cs.x, s1 = cs.y;
    const float c2 = c1 + c1;
    float prev = ttype ? 0.f : 1.f;
    float cur  = ttype ? s1 : c1;
    uint4* dst = (uint4*)&AsDst[frow * LDA + ihalf * 32];
    unsigned int us[4];
    #pragma unroll
    for (int d = 0; d < 16; ++d) {
        float f0 = cur;
        float f1 = __builtin_fmaf(c2, cur, -prev);
        float f2 = __builtin_fmaf(c2, f1, -cur);
        prev = f1;
        cur = f2;
        us[d & 3] = pack2bf(f0, f1);
        if ((d & 3) == 3)
            dst[d >> 2] = make_uint4(us[0], us[1], us[2], us[3]);
    }
}

__device__ inline void load_B(short8 b[2][4], const unsigned short* Bbase, int iter) {
    #pragma unroll
    for (int h = 0; h < 2; ++h)
        #pragma unroll
        for (int tn = 0; tn < 4; ++tn)
            b[h][tn] = *(const short8*)(Bbase + (size_t)tn * 16 * KT + iter * 64 + h * 32);
}

__device__ inline void do_mfma(float4v acc[4][4], const unsigned short* AsP,
                               short8 b[2][4], int wm, int lm, int lq) {
    #pragma unroll
    for (int h = 0; h < 2; ++h) {
        short8 af[4];
        #pragma unroll
        for (int tm = 0; tm < 4; ++tm)
            af[tm] = *(const short8*)&AsP[(wm + tm * 16 + lm) * LDA + h * 32 + lq * 8];
        #pragma unroll
        for (int tm = 0; tm < 4; ++tm)
            #pragma unroll
            for (int tn = 0; tn < 4; ++tn)
                acc[tm][tn] = __builtin_amdgcn_mfma_f32_16x16x32_bf16(
                    af[tm], b[h][tn], acc[tm][tn], 0, 0, 0);
    }
}

// ---- kernel 4: fused feature-gen + bf16 MFMA GEMM, split-K=8 ----
// grid (32 row-tiles, 4 col-tiles, 8 k-chunks); chunk>>2 = trig (0 cos / 1 sin)
// A: Chebyshev features, double-buffered LDS, ONE barrier/iter.
// B: direct global 16B frags, full-iteration register ping-pong (b0/b1).
__global__ __launch_bounds__(256, 3) void fkan_gemm(const float2* __restrict__ csT,
        const unsigned short* __restrict__ Wb, unsigned short* __restrict__ pb) {
    __shared__ unsigned short As[2][BM * LDA];
    const int t = threadIdx.x;
    const int row0 = blockIdx.x * BM;
    const int col0 = blockIdx.y * BN;
    const int chunk = blockIdx.z;
    const int ttype = chunk >> 2;
    const int k0 = (chunk & 3) * 4096;   // within-trig k offset
    const int i0 = k0 >> 5;              // starting input dim for this chunk
    const int frow = t & 127;
    const int ihalf = t >> 7;
    const int l = t & 63, wv = t >> 6;
    const int wm = (wv & 1) * 64, wn = (wv >> 1) * 64;
    const int lm = l & 15, lq = l >> 4;

    // per-lane B base: col = col0+wn+tn*16+lm (tn via +16*KT), k = k0+lq*8
    const unsigned short* Bbase = Wb + (size_t)ttype * D_OUT * KT
                                + (size_t)(col0 + wn + lm) * KT + k0 + lq * 8;
    const float2* csBase = csT + (size_t)i0 * N_ROWS + row0 + frow
                         + (size_t)ihalf * N_ROWS;

    float4v acc[4][4];
    #pragma unroll
    for (int i = 0; i < 4; ++i)
        #pragma unroll
        for (int j = 0; j < 4; ++j)
            acc[i][j] = (float4v){0.f, 0.f, 0.f, 0.f};

    // prologue: B(0) into b0, features(0) into As[0], seeds(1) into cs
    short8 b0[2][4], b1[2][4];
    load_B(b0, Bbase, 0);
    float2 cs = csBase[0];
    stage_feats(As[0], cs, ttype, frow, ihalf);
    cs = csBase[2 * N_ROWS];
    __syncthreads();

    for (int iter = 0; iter < 64; iter += 2) {
        // ---- even body: MFMA(As[0], b0); prefetch B(iter+1)->b1, feats(iter+1)->As[1]
        load_B(b1, Bbase, iter + 1);
        stage_feats(As[1], cs, ttype, frow, ihalf);             // iter+1 (always valid)
        if (iter < 62)
            cs = csBase[(size_t)(iter + 2) * 2 * N_ROWS];       // seeds(iter+2)
        do_mfma(acc, As[0], b0, wm, lm, lq);
        __syncthreads();
        // ---- odd body: MFMA(As[1], b1); prefetch B(iter+2)->b0, feats(iter+2)->As[0]
        if (iter < 62) {
            load_B(b0, Bbase, iter + 2);
            stage_feats(As[0], cs, ttype, frow, ihalf);         // iter+2
        }
        if (iter < 61)
            cs = csBase[(size_t)(iter + 3) * 2 * N_ROWS];       // seeds(iter+3)
        do_mfma(acc, As[1], b1, wm, lm, lq);
        __syncthreads();
    }
    // epilogue: C/D layout col=lane&15, row=quad*4+reg (m89-verified)
    unsigned short* pc = pb + (size_t)chunk * N_ROWS * D_OUT;
    #pragma unroll
    for (int tm = 0; tm < 4; ++tm)
        #pragma unroll
        for (int tn = 0; tn < 4; ++tn)
            #pragma unroll
            for (int r = 0; r < 4; ++r) {
                const int row = row0 + wm + tm * 16 + lq * 4 + r;
                const int col = col0 + wn + tn * 16 + lm;
                pc[(size_t)row * D_OUT + col] = bf16_1(acc[tm][tn][r]);
            }
}

// ---- kernel 5: out = bias + sum of 8 bf16 partials (coalesced) ----
__global__ __launch_bounds__(256) void reduce_kernel(const unsigned short* __restrict__ pb,
        const float* __restrict__ bias, float* __restrict__ out) {
    const size_t e = ((size_t)blockIdx.x * 256 + threadIdx.x) * 4;
    const int col = (int)(e & (D_OUT - 1));
    float4 s = *(const float4*)(bias + col);
    #pragma unroll
    for (int c = 0; c < 8; ++c) {
        ushort4 u = *(const ushort4*)(pb + (size_t)c * N_ROWS * D_OUT + e);
        union { unsigned int u; float f; } f0, f1, f2, f3;
        f0.u = (unsigned int)u.x << 16;
        f1.u = (unsigned int)u.y << 16;
        f2.u = (unsigned int)u.z << 16;
        f3.u = (unsigned int)u.w << 16;
        s.x += f0.f; s.y += f1.f; s.z += f2.f; s.w += f3.f;
    }
    *(float4*)(out + e) = s;
}

extern "C" void kernel_launch(void* const* d_in, const int* in_sizes, int n_in,
                              void* d_out, int out_size, void* d_ws, size_t ws_size,
                              hipStream_t stream) {
    const float* x    = (const float*)d_in[0];
    const float* ln_w = (const float*)d_in[1];
    const float* ln_b = (const float*)d_in[2];
    const float* fc   = (const float*)d_in[3];
    const float* bias = (const float*)d_in[4];
    float* out = (float*)d_out;

    float2* csT = (float2*)d_ws;                                        // 16 MB
    float2* mu_rs = (float2*)((char*)d_ws + (16u << 20));               // 32 KB
    unsigned short* Wb = (unsigned short*)((char*)d_ws + (17u << 20));  // 33.5 MB
    unsigned short* pbp = (unsigned short*)((char*)d_ws + (51u << 20)); // 33.5 MB

    ln_stats<<<N_ROWS / 4, 256, 0, stream>>>(x, mu_rs);
    feat_seed<<<dim3(N_ROWS / 64, D_IN / 64), 256, 0, stream>>>(x, ln_w, ln_b, mu_rs, csT);
    cvt_kernel<<<8192, 256, 0, stream>>>(fc, Wb);                       // 16.78M elems
    fkan_gemm<<<dim3(N_ROWS / BM, D_OUT / BN, 8), 256, 0, stream>>>(csT, Wb, pbp);
    reduce_kernel<<<2048, 256, 0, stream>>>(pbp, bias, out);            // 2.10M outs
}

// Round 7
// 312.477 us; speedup vs baseline: 1.9489x; 1.7406x over previous
//
#include <hip/hip_runtime.h>
#include <hip/hip_bf16.h>

// FourierKANLayer: N=4096, D_IN=512, D_OUT=512, G=32
// y = [cos/sin(k*LN(x)) features] @ W + bias  == GEMM M=4096,N=512,K=32768 (bf16 MFMA)
// R7: A dbuf LDS (XOR-swizzled, no pad) + B dbuf LDS staged via
//     global_load_lds width=16 (coalesced, zero VGPR). One barrier/iter.
//     Split-K=4, cos+sin merged in one 128-iter K-loop. 64KB LDS, 2 blocks/CU.
// ws layout: [0,16MB)  csT float2[512][4096] = (cos xn, sin xn) transposed seeds
//            [16MB]    mu_rs float2[4096] (32 KB)
//            [17MB]    bf16 weights [2][512][16384] K-major (33.5 MB)
//            [51MB]    bf16 split-K partials [4][4096][512] (16.8 MB)

#define N_ROWS 4096
#define D_IN   512
#define D_OUT  512
#define KT     16384   // per-trig K = D_IN*G
#define BM 128
#define BN 128
#define SPLITK 4

typedef short short8 __attribute__((ext_vector_type(8)));
typedef float float4v __attribute__((ext_vector_type(4)));

__device__ inline unsigned int pack2bf(float a, float b) {
    __hip_bfloat162 h = __float22bfloat162_rn(make_float2(a, b));
    union { __hip_bfloat162 h; unsigned int u; } cv;
    cv.h = h;
    return cv.u;
}

__device__ inline unsigned short bf16_1(float a) {
    union { float f; unsigned int u; } cv;
    cv.f = a;
    unsigned int r = (cv.u + 0x7fff + ((cv.u >> 16) & 1)) >> 16;  // RN-even
    return (unsigned short)r;
}

// ---- kernel 1: per-row LayerNorm stats (mu, rsqrt(var+eps)) ----
__global__ __launch_bounds__(256) void ln_stats(const float* __restrict__ x,
        float2* __restrict__ mu_rs) {
    const int t = threadIdx.x;
    const int row = blockIdx.x * 4 + (t >> 6);
    const int lane = t & 63;
    const float4* xr = (const float4*)(x + (size_t)row * D_IN);
    float4 a = xr[lane];
    float4 c = xr[lane + 64];
    float s = a.x + a.y + a.z + a.w + c.x + c.y + c.z + c.w;
    float q = a.x * a.x + a.y * a.y + a.z * a.z + a.w * a.w
            + c.x * c.x + c.y * c.y + c.z * c.z + c.w * c.w;
    #pragma unroll
    for (int off = 32; off > 0; off >>= 1) {
        s += __shfl_down(s, off, 64);
        q += __shfl_down(q, off, 64);
    }
    if (lane == 0) {
        float mu = s * (1.f / D_IN);
        float var = q * (1.f / D_IN) - mu * mu;
        mu_rs[row] = make_float2(mu, rsqrtf(var + 1e-5f));
    }
}

// ---- kernel 2: normalize + sincos seeds, transposed coalesced write ----
__global__ __launch_bounds__(256) void feat_seed(const float* __restrict__ x,
        const float* __restrict__ w, const float* __restrict__ b,
        const float2* __restrict__ mu_rs, float2* __restrict__ csT) {
    __shared__ float2 tile[64][66];
    const int t = threadIdx.x;
    const int r0 = blockIdx.x * 64, i0 = blockIdx.y * 64;
    const int rr = t >> 6;      // 0..3
    const int cc = t & 63;
    const float wv = w[i0 + cc], bv = b[i0 + cc];
    #pragma unroll
    for (int p = 0; p < 16; ++p) {
        const int row = r0 + p * 4 + rr;
        float v = x[(size_t)row * D_IN + i0 + cc];
        float2 mr = mu_rs[row];
        float xn = (v - mr.x) * mr.y * wv + bv;
        float sn, cn;
        __sincosf(xn, &sn, &cn);
        tile[cc][p * 4 + rr] = make_float2(cn, sn);
    }
    __syncthreads();
    #pragma unroll
    for (int p = 0; p < 16; ++p) {
        const int dim = p * 4 + rr;
        csT[(size_t)(i0 + dim) * N_ROWS + r0 + cc] = tile[dim][cc];
    }
}

// ---- kernel 3: cast fouriercoeffs fp32 -> bf16 (layout preserved: [t][o][i*32+g]) ----
__global__ __launch_bounds__(256) void cvt_kernel(const float* __restrict__ fc,
        unsigned short* __restrict__ Wb) {
    size_t e = ((size_t)blockIdx.x * 256 + threadIdx.x) * 8;
    const float4* in = (const float4*)(fc + e);
    float4 a = in[0];
    float4 c = in[1];
    uint4 o;
    o.x = pack2bf(a.x, a.y);
    o.y = pack2bf(a.z, a.w);
    o.z = pack2bf(c.x, c.y);
    o.w = pack2bf(c.z, c.w);
    *(uint4*)(Wb + e) = o;
}

// ---- feature staging: Chebyshev chain -> swizzled A LDS tile ----
// A layout: [row][64 shorts], 16B chunk kc stored at chunk index kc^(row&7).
__device__ inline void stage_feats(unsigned short* Abuf, float2 cs, int ttype,
                                   int frow, int ihalf) {
    const float c1 = cs.x, s1 = cs.y;
    const float c2 = c1 + c1;
    float prev = ttype ? 0.f : 1.f;
    float cur  = ttype ? s1 : c1;
    const int rbase = frow * 64;
    const int sw = frow & 7;
    unsigned int us[4];
    #pragma unroll
    for (int d = 0; d < 16; ++d) {
        float f0 = cur;
        float f1 = __builtin_fmaf(c2, cur, -prev);
        float f2 = __builtin_fmaf(c2, f1, -cur);
        prev = f1;
        cur = f2;
        us[d & 3] = pack2bf(f0, f1);
        if ((d & 3) == 3) {
            const int kc = ihalf * 4 + (d >> 2);
            *(uint4*)&Abuf[rbase + ((kc ^ sw) << 3)] =
                make_uint4(us[0], us[1], us[2], us[3]);
        }
    }
}

// ---- kernel 4: fused feature-gen + bf16 MFMA GEMM, split-K=4, trig-merged ----
// grid (32 row-tiles, 4 col-tiles, 4 k-chunks). 128 K-iters: 0..63 cos, 64..127 sin.
__global__ __launch_bounds__(256, 2) void fkan_gemm(const float2* __restrict__ csT,
        const unsigned short* __restrict__ Wb, unsigned short* __restrict__ pb) {
    __shared__ unsigned short As[2][BM * 64];   // 2 x 16 KB, swizzled
    __shared__ unsigned short Bs[2][BN * 64];   // 2 x 16 KB, [colgrp][seg][col&7][8sh]
    const int t = threadIdx.x;
    const int row0 = blockIdx.x * BM;
    const int col0 = blockIdx.y * BN;
    const int kz = blockIdx.z;
    const int k0 = kz * 4096;            // within-trig k offset
    const int i0 = kz * 128;             // starting input dim for this chunk
    const int frow = t & 127;            // A-staging row
    const int ihalf = t >> 7;            // which of the 2 dims per iter
    const int l = t & 63, wv = t >> 6;
    const int wm = (wv & 1) * 64, wn = (wv >> 1) * 64;
    const int lm = l & 15, lq = l >> 4;
    // gl_lds B staging: wave wv covers cols [col0+wv*32, +32), 4 instr x (8 cols x 128B)
    const int c8 = l & 7, s8 = l >> 3;   // lane -> (col-within-8, 16B-segment)
    const unsigned short* Bg0 = Wb + (size_t)(col0 + wv * 32 + c8) * KT + k0 + s8 * 8;
    // A-frag read offsets (swizzled)
    const int swA = lm & 7;
    // B-frag read base (shorts): gi*512 + s*64 + ci*8
    const int bBase = ((wn >> 3) + (lm >> 3)) * 512 + lq * 64 + (lm & 7) * 8;

    const float2* csBase = csT + (size_t)(i0 + ihalf) * N_ROWS + row0 + frow;

    float4v acc[4][4];
    #pragma unroll
    for (int i = 0; i < 4; ++i)
        #pragma unroll
        for (int j = 0; j < 4; ++j)
            acc[i][j] = (float4v){0.f, 0.f, 0.f, 0.f};

    // prologue: B(0) -> Bs[0] (async), A(0) -> As[0], seeds(1)
    #pragma unroll
    for (int j = 0; j < 4; ++j) {
        const unsigned short* gsrc = Bg0 + (size_t)(j * 8) * KT;   // ttype=0, ii=0
        unsigned short* ldst = &Bs[0][(wv * 4 + j) * 512];
        __builtin_amdgcn_global_load_lds(
            (const __attribute__((address_space(1))) unsigned int*)gsrc,
            (__attribute__((address_space(3))) unsigned int*)ldst, 16, 0, 0);
    }
    float2 cs = csBase[0];
    stage_feats(As[0], cs, 0, frow, ihalf);
    cs = csBase[2 * N_ROWS];             // seeds for iter 1
    __syncthreads();

    for (int iter = 0; iter < 128; ++iter) {
        const int p = iter & 1;
        if (iter < 127) {
            const int in = iter + 1;
            const int tt = in >> 6, ii = in & 63;
            const unsigned short* gb = Bg0 + (size_t)tt * D_OUT * KT + ii * 64;
            #pragma unroll
            for (int j = 0; j < 4; ++j) {
                const unsigned short* gsrc = gb + (size_t)(j * 8) * KT;
                unsigned short* ldst = &Bs[p ^ 1][(wv * 4 + j) * 512];
                __builtin_amdgcn_global_load_lds(
                    (const __attribute__((address_space(1))) unsigned int*)gsrc,
                    (__attribute__((address_space(3))) unsigned int*)ldst, 16, 0, 0);
            }
            stage_feats(As[p ^ 1], cs, tt, frow, ihalf);
        }
        if (iter < 126)
            cs = csBase[(size_t)(((iter + 2) & 63) * 2) * N_ROWS];  // seeds(iter+2)
        // ---- MFMA on As[p], Bs[p]
        #pragma unroll
        for (int h = 0; h < 2; ++h) {
            short8 af[4], bf[4];
            #pragma unroll
            for (int tm = 0; tm < 4; ++tm)
                af[tm] = *(const short8*)
                    &As[p][(wm + tm * 16 + lm) * 64 + (((h * 4 + lq) ^ swA) << 3)];
            #pragma unroll
            for (int tn = 0; tn < 4; ++tn)
                bf[tn] = *(const short8*)&Bs[p][bBase + tn * 1024 + h * 256];
            #pragma unroll
            for (int tm = 0; tm < 4; ++tm)
                #pragma unroll
                for (int tn = 0; tn < 4; ++tn)
                    acc[tm][tn] = __builtin_amdgcn_mfma_f32_16x16x32_bf16(
                        af[tm], bf[tn], acc[tm][tn], 0, 0, 0);
        }
        __syncthreads();   // publishes (p^1) staging, protects (p) for overwrite
    }
    // epilogue: C/D layout col=lane&15, row=quad*4+reg (m89-verified)
    unsigned short* pc = pb + (size_t)kz * N_ROWS * D_OUT;
    #pragma unroll
    for (int tm = 0; tm < 4; ++tm)
        #pragma unroll
        for (int tn = 0; tn < 4; ++tn)
            #pragma unroll
            for (int r = 0; r < 4; ++r) {
                const int row = row0 + wm + tm * 16 + lq * 4 + r;
                const int col = col0 + wn + tn * 16 + lm;
                pc[(size_t)row * D_OUT + col] = bf16_1(acc[tm][tn][r]);
            }
}

// ---- kernel 5: out = bias + sum of 4 bf16 partials (coalesced) ----
__global__ __launch_bounds__(256) void reduce_kernel(const unsigned short* __restrict__ pb,
        const float* __restrict__ bias, float* __restrict__ out) {
    const size_t e = ((size_t)blockIdx.x * 256 + threadIdx.x) * 4;
    const int col = (int)(e & (D_OUT - 1));
    float4 s = *(const float4*)(bias + col);
    #pragma unroll
    for (int c = 0; c < SPLITK; ++c) {
        ushort4 u = *(const ushort4*)(pb + (size_t)c * N_ROWS * D_OUT + e);
        union { unsigned int u; float f; } f0, f1, f2, f3;
        f0.u = (unsigned int)u.x << 16;
        f1.u = (unsigned int)u.y << 16;
        f2.u = (unsigned int)u.z << 16;
        f3.u = (unsigned int)u.w << 16;
        s.x += f0.f; s.y += f1.f; s.z += f2.f; s.w += f3.f;
    }
    *(float4*)(out + e) = s;
}

extern "C" void kernel_launch(void* const* d_in, const int* in_sizes, int n_in,
                              void* d_out, int out_size, void* d_ws, size_t ws_size,
                              hipStream_t stream) {
    const float* x    = (const float*)d_in[0];
    const float* ln_w = (const float*)d_in[1];
    const float* ln_b = (const float*)d_in[2];
    const float* fc   = (const float*)d_in[3];
    const float* bias = (const float*)d_in[4];
    float* out = (float*)d_out;

    float2* csT = (float2*)d_ws;                                        // 16 MB
    float2* mu_rs = (float2*)((char*)d_ws + (16u << 20));               // 32 KB
    unsigned short* Wb = (unsigned short*)((char*)d_ws + (17u << 20));  // 33.5 MB
    unsigned short* pbp = (unsigned short*)((char*)d_ws + (51u << 20)); // 16.8 MB

    ln_stats<<<N_ROWS / 4, 256, 0, stream>>>(x, mu_rs);
    feat_seed<<<dim3(N_ROWS / 64, D_IN / 64), 256, 0, stream>>>(x, ln_w, ln_b, mu_rs, csT);
    cvt_kernel<<<8192, 256, 0, stream>>>(fc, Wb);                       // 16.78M elems
    fkan_gemm<<<dim3(N_ROWS / BM, D_OUT / BN, SPLITK), 256, 0, stream>>>(csT, Wb, pbp);
    reduce_kernel<<<2048, 256, 0, stream>>>(pbp, bias, out);            // 2.10M outs
}